// Round 3
// baseline (472.279 us; speedup 1.0000x reference)
//
#include <hip/hip_runtime.h>
#include <math.h>

// MoE gate, round 3. Two kernels:
//  K1 (logits): grid 1024 = 256 token-tiles x 4 expert-groups; block = 1024thr
//     = 16 waves. lane = token (64/tile); wave = 16 experts x 128-wide K-slice
//     -> acc[16]/lane, full K covered by the block's 16 waves; deterministic
//     LDS reduce; logits -> d_ws [16384][64] fp32.
//     w loads: VGPR-opaque base defeats scalarization -> broadcast
//     global_load_dwordx4 (in-order vmcnt pipelining, no lgkmcnt(0) stalls —
//     round-2's 50% VALUBusy was s_load batch serialization).
//  K2 (top-8): 1 thread/token, selection top-8 (strict >, lax.top_k ties),
//     softmax over top-8 (== full softmax renormalized), store.

#define H_DIM 2048
#define N_EXP 64
#define TOPK 8
#define TOK_TILE 64
#define EG_SZ 16                  // experts per block
#define N_WAVE 16
#define K_SLICE (H_DIM / N_WAVE)  // 128

__global__ __launch_bounds__(1024, 8) void moe_logits_kernel(
    const float* __restrict__ x, const float* __restrict__ w,
    float* __restrict__ logits) {
  const int lane = threadIdx.x & 63;
  const int ws = threadIdx.x >> 6;
  const int tile = blockIdx.x >> 2;
  const int eg = blockIdx.x & 3;
  const int t = tile * TOK_TILE + lane;

  // Lane-opaque zero: forces w addresses to VGPRs -> vector broadcast loads.
  int vzero;
  asm("v_mov_b32 %0, 0" : "=v"(vzero));

  float acc[EG_SZ];
#pragma unroll
  for (int e = 0; e < EG_SZ; ++e) acc[e] = 0.f;

  const float* xrow = x + (size_t)t * H_DIM + ws * K_SLICE;
  const float* wbase =
      w + (size_t)(eg * EG_SZ) * H_DIM + ws * K_SLICE + vzero;

  for (int o = 0; o < K_SLICE / 8; ++o) {
    const float4* xq = reinterpret_cast<const float4*>(xrow + o * 8);
    const float4 xa = xq[0];
    const float4 xb = xq[1];
#pragma unroll
    for (int e = 0; e < EG_SZ; ++e) {
      const float4* wq =
          reinterpret_cast<const float4*>(wbase + (size_t)e * H_DIM + o * 8);
      const float4 wa = wq[0];
      const float4 wb = wq[1];
      float a = acc[e];
      a = fmaf(xa.x, wa.x, a);
      a = fmaf(xa.y, wa.y, a);
      a = fmaf(xa.z, wa.z, a);
      a = fmaf(xa.w, wa.w, a);
      a = fmaf(xb.x, wb.x, a);
      a = fmaf(xb.y, wb.y, a);
      a = fmaf(xb.z, wb.z, a);
      a = fmaf(xb.w, wb.w, a);
      acc[e] = a;
    }
  }

  // deterministic cross-wave reduce: dump all 16 partial sets, fixed-order sum
  __shared__ float red[N_WAVE][EG_SZ][TOK_TILE];  // 64 KB
#pragma unroll
  for (int e = 0; e < EG_SZ; ++e) red[ws][e][lane] = acc[e];
  __syncthreads();

  const int re = threadIdx.x >> 6;  // expert within group, 0..15
  const int rt = threadIdx.x & 63;  // token within tile
  float s = 0.f;
#pragma unroll
  for (int w2 = 0; w2 < N_WAVE; ++w2) s += red[w2][re][rt];
  logits[(size_t)(tile * TOK_TILE + rt) * N_EXP + eg * EG_SZ + re] = s;
}

__global__ __launch_bounds__(64, 4) void moe_topk_kernel(
    const float* __restrict__ logits, float* __restrict__ out, int n_tokens) {
  const int t = blockIdx.x * 64 + threadIdx.x;

  float lg[N_EXP];
  const float4* lq = reinterpret_cast<const float4*>(logits + (size_t)t * N_EXP);
#pragma unroll
  for (int q = 0; q < N_EXP / 4; ++q) {
    float4 v = lq[q];
    lg[q * 4 + 0] = v.x;
    lg[q * 4 + 1] = v.y;
    lg[q * 4 + 2] = v.z;
    lg[q * 4 + 3] = v.w;
  }

  float bw[TOPK];
  int bi[TOPK];
#pragma unroll
  for (int k = 0; k < TOPK; ++k) {
    float m = lg[0];
    int mi = 0;
#pragma unroll
    for (int e = 1; e < N_EXP; ++e) {
      if (lg[e] > m) {  // strict > keeps lowest index on tie (lax.top_k)
        m = lg[e];
        mi = e;
      }
    }
    bw[k] = m;
    bi[k] = mi;
#pragma unroll
    for (int e = 0; e < N_EXP; ++e)
      if (e == mi) lg[e] = -INFINITY;
  }

  const float mx = bw[0];
  float ew[TOPK];
  float s = 0.f;
#pragma unroll
  for (int k = 0; k < TOPK; ++k) {
    ew[k] = expf(bw[k] - mx);
    s += ew[k];
  }
  const float inv = 1.f / s;

  float4 w0, w1, i0, i1;
  w0.x = ew[0] * inv; w0.y = ew[1] * inv; w0.z = ew[2] * inv; w0.w = ew[3] * inv;
  w1.x = ew[4] * inv; w1.y = ew[5] * inv; w1.z = ew[6] * inv; w1.w = ew[7] * inv;
  i0.x = (float)bi[0]; i0.y = (float)bi[1]; i0.z = (float)bi[2]; i0.w = (float)bi[3];
  i1.x = (float)bi[4]; i1.y = (float)bi[5]; i1.z = (float)bi[6]; i1.w = (float)bi[7];

  float4* ow = reinterpret_cast<float4*>(out + (size_t)t * TOPK);
  ow[0] = w0;
  ow[1] = w1;
  float4* oi =
      reinterpret_cast<float4*>(out + (size_t)n_tokens * TOPK + (size_t)t * TOPK);
  oi[0] = i0;
  oi[1] = i1;
}

extern "C" void kernel_launch(void* const* d_in, const int* in_sizes, int n_in,
                              void* d_out, int out_size, void* d_ws,
                              size_t ws_size, hipStream_t stream) {
  const float* x = (const float*)d_in[0];
  const float* w = (const float*)d_in[1];
  float* out = (float*)d_out;
  float* logits = (float*)d_ws;  // [16384][64] fp32 = 4 MB
  const int n_tokens = in_sizes[0] / H_DIM;  // 16384

  const int n_blocks1 = (n_tokens / TOK_TILE) * (N_EXP / EG_SZ);  // 1024
  moe_logits_kernel<<<n_blocks1, 1024, 0, stream>>>(x, w, logits);

  const int n_blocks2 = n_tokens / 64;  // 256
  moe_topk_kernel<<<n_blocks2, 64, 0, stream>>>(logits, out, n_tokens);
}